// Round 4
// baseline (52.999 us; speedup 1.0000x reference)
//
#include <hip/hip_runtime.h>

#define B_ROWS 32768
#define NPROTO 2048
#define NOUT   200
#define LAT    40
#define PBLK   16      // proto-reduction blocks in stage1
#define FBLK   1024    // fused-kernel blocks
#define RPB    32      // rows per fused block

// ws layout (floats):
//  [0..199]      wsum[200]
//  [200..215]    proto_sq partials (16)
//  [256..895]    proto_sum partials [16][40]
//  [1024..2047]  block min partials (1024)
//  [2048..3071]  block sum partials (1024)
//  [3072]        arrival counter (int), reset by stage1 each call

__global__ __launch_bounds__(320) void pc_stage1(const float* __restrict__ protos,
                                                 const float* __restrict__ w,
                                                 float* __restrict__ ws) {
    const int b = blockIdx.x;
    const int t = threadIdx.x;
    __shared__ float sred[5];
    __shared__ float sdim[8][40];
    __shared__ float ssq[5];
    if (b == 0 && t == 0) ((int*)ws)[3072] = 0;   // reset arrival counter every call
    if (b < NOUT) {
        // wsum[b] = sum_p w[b, p] — coalesced, 7 iters
        float acc = 0.f;
        const float* row = w + b * NPROTO;
        for (int k = t; k < NPROTO; k += 320) acc += row[k];
        #pragma unroll
        for (int off = 32; off > 0; off >>= 1) acc += __shfl_down(acc, off, 64);
        if ((t & 63) == 0) sred[t >> 6] = acc;
        __syncthreads();
        if (t == 0) ws[b] = sred[0] + sred[1] + sred[2] + sred[3] + sred[4];
    } else {
        // proto partial reduction: 16 blocks x 320 threads, d = t%40 invariant
        const int rel = b - NOUT;          // 0..15
        const int d = t % 40, g = t / 40;  // 8 groups of 40
        float sum = 0.f, sq = 0.f;
        for (int idx = rel * 320 + t; idx < NPROTO * LAT; idx += PBLK * 320) {
            float v = protos[idx];          // coalesced; idx%40 == d always
            sum += v;
            sq  += v * v;
        }
        sdim[g][d] = sum;
        #pragma unroll
        for (int off = 32; off > 0; off >>= 1) sq += __shfl_down(sq, off, 64);
        if ((t & 63) == 0) ssq[t >> 6] = sq;
        __syncthreads();
        if (t < 40) {
            float s = 0.f;
            #pragma unroll
            for (int g2 = 0; g2 < 8; ++g2) s += sdim[g2][t];
            ws[256 + rel * 40 + t] = s;
        }
        if (t == 0) ws[200 + rel] = ssq[0] + ssq[1] + ssq[2] + ssq[3] + ssq[4];
    }
}

__global__ __launch_bounds__(256) void pc_fused(const float* __restrict__ x,
                                                const float* __restrict__ bias,
                                                float* __restrict__ ws,
                                                float* __restrict__ out) {
    __shared__ float sps[40];
    __shared__ float spsq;
    __shared__ float2 swb[100];   // wsum pairs
    __shared__ float2 sbb[100];   // bias pairs
    __shared__ float sd[RPB];
    __shared__ int   islast;
    __shared__ float fmn[4], fsm[4];
    const int t   = threadIdx.x;
    const int blk = blockIdx.x;

    // fold stage1 partials (L2-hot) + stage wsum/bias into LDS
    if (t < 40) {
        float s = 0.f;
        #pragma unroll
        for (int j = 0; j < PBLK; ++j) s += ws[256 + j * 40 + t];
        sps[t] = s;
    } else if (t == 40) {
        float s = 0.f;
        #pragma unroll
        for (int j = 0; j < PBLK; ++j) s += ws[200 + j];
        spsq = s;
    }
    if (t >= 56 && t < 156) swb[t - 56]  = ((const float2*)ws)[t - 56];
    if (t >= 156)           sbb[t - 156] = ((const float2*)bias)[t - 156];
    __syncthreads();

    // phase 1: threads 0..31 compute d for this block's 32 rows
    if (t < RPB) {
        const int row = blk * RPB + t;
        const float4* xr = (const float4*)(x + row * LAT);
        float ssq = 0.f, dot = 0.f;
        #pragma unroll
        for (int k = 0; k < 10; ++k) {
            float4 v = xr[k];
            ssq += v.x * v.x + v.y * v.y + v.z * v.z + v.w * v.w;
            dot += v.x * sps[4 * k] + v.y * sps[4 * k + 1] +
                   v.z * sps[4 * k + 2] + v.w * sps[4 * k + 3];
        }
        const float d = sqrtf(2048.f * ssq - 2.f * dot + spsq);
        sd[t] = d;
        float mn = d, sm = d;
        #pragma unroll
        for (int off = 16; off > 0; off >>= 1) {   // 32 active lanes
            mn = fminf(mn, __shfl_down(mn, off, 64));
            sm += __shfl_down(sm, off, 64);
        }
        if (t == 0) {
            ws[1024 + blk] = mn;
            ws[2048 + blk] = sm;
        }
    }
    __syncthreads();

    // phase 2: write this block's 32x200 output slab (3200 float2 pairs)
    float2* o = (float2*)(out + 2);          // 8B-aligned
    const int base = blk * (RPB * 100);
    for (int idx = t; idx < RPB * 100; idx += 256) {
        const int i = idx / 100;             // row within block (magic-mul)
        const int j = idx - i * 100;         // column pair
        const float  dd = sd[i];
        const float2 wv = swb[j];
        const float2 bv = sbb[j];
        float2 r;
        r.x = dd * wv.x + bv.x;
        r.y = dd * wv.y + bv.y;
        o[base + idx] = r;
    }

    // last-block grid reduction for out[0..1]
    if (t == 0) {
        __threadfence();
        int prev = atomicAdd((int*)ws + 3072, 1);
        islast = (prev == FBLK - 1);
    }
    __syncthreads();
    if (islast) {
        __threadfence();
        float m2 = fminf(fminf(ws[1024 + t],       ws[1024 + 256 + t]),
                         fminf(ws[1024 + 512 + t], ws[1024 + 768 + t]));
        float s2 = ws[2048 + t] + ws[2048 + 256 + t] +
                   ws[2048 + 512 + t] + ws[2048 + 768 + t];
        #pragma unroll
        for (int off = 32; off > 0; off >>= 1) {
            m2 = fminf(m2, __shfl_down(m2, off, 64));
            s2 += __shfl_down(s2, off, 64);
        }
        if ((t & 63) == 0) { fmn[t >> 6] = m2; fsm[t >> 6] = s2; }
        __syncthreads();
        if (t == 0) {
            out[0] = fminf(fminf(fmn[0], fmn[1]), fminf(fmn[2], fmn[3]));
            out[1] = (fsm[0] + fsm[1] + fsm[2] + fsm[3]) * (1.0f / 32768.0f);
        }
    }
}

extern "C" void kernel_launch(void* const* d_in, const int* in_sizes, int n_in,
                              void* d_out, int out_size, void* d_ws, size_t ws_size,
                              hipStream_t stream) {
    const float* x      = (const float*)d_in[0];
    const float* protos = (const float*)d_in[1];
    const float* w      = (const float*)d_in[2];
    const float* bias   = (const float*)d_in[3];
    float* out = (float*)d_out;
    float* ws  = (float*)d_ws;

    pc_stage1<<<NOUT + PBLK, 320, 0, stream>>>(protos, w, ws);
    pc_fused<<<FBLK, 256, 0, stream>>>(x, bias, ws, out);
}

// Round 5
// 19.483 us; speedup vs baseline: 2.7203x; 2.7203x over previous
//
#include <hip/hip_runtime.h>

#define B_ROWS 32768
#define NPROTO 2048
#define NOUT   200
#define LAT    40
#define PBLK   16      // proto-reduction blocks in stage1
#define FBLK   2048    // fused dist+out blocks
#define RPB    16      // rows per fused block

// ws layout (floats):
//  [0..199]      wsum[200]
//  [200..215]    proto_sq partials (16)
//  [256..895]    proto_sum partials [16][40]
//  [1024..3071]  block min partials (2048)
//  [3072..5119]  block sum partials (2048)

__global__ __launch_bounds__(320) void pc_stage1(const float* __restrict__ protos,
                                                 const float* __restrict__ w,
                                                 float* __restrict__ ws) {
    const int b = blockIdx.x;
    const int t = threadIdx.x;
    __shared__ float sred[5];
    __shared__ float sdim[8][40];
    __shared__ float ssq[5];
    if (b < NOUT) {
        // wsum[b] = sum_p w[b, p] — coalesced, 7 iters
        float acc = 0.f;
        const float* row = w + b * NPROTO;
        for (int k = t; k < NPROTO; k += 320) acc += row[k];
        #pragma unroll
        for (int off = 32; off > 0; off >>= 1) acc += __shfl_down(acc, off, 64);
        if ((t & 63) == 0) sred[t >> 6] = acc;
        __syncthreads();
        if (t == 0) ws[b] = sred[0] + sred[1] + sred[2] + sred[3] + sred[4];
    } else {
        // proto partial reduction: 16 blocks x 320 threads, d = t%40 invariant
        const int rel = b - NOUT;          // 0..15
        const int d = t % 40, g = t / 40;  // 8 groups of 40
        float sum = 0.f, sq = 0.f;
        for (int idx = rel * 320 + t; idx < NPROTO * LAT; idx += PBLK * 320) {
            float v = protos[idx];          // coalesced; idx%40 == d always
            sum += v;
            sq  += v * v;
        }
        sdim[g][d] = sum;
        #pragma unroll
        for (int off = 32; off > 0; off >>= 1) sq += __shfl_down(sq, off, 64);
        if ((t & 63) == 0) ssq[t >> 6] = sq;
        __syncthreads();
        if (t < 40) {
            float s = 0.f;
            #pragma unroll
            for (int g2 = 0; g2 < 8; ++g2) s += sdim[g2][t];
            ws[256 + rel * 40 + t] = s;
        }
        if (t == 0) ws[200 + rel] = ssq[0] + ssq[1] + ssq[2] + ssq[3] + ssq[4];
    }
}

__global__ __launch_bounds__(256) void pc_distout(const float* __restrict__ x,
                                                  const float* __restrict__ bias,
                                                  float* __restrict__ ws,
                                                  float* __restrict__ out) {
    __shared__ float sps[40];
    __shared__ float spsq;
    __shared__ float2 swb[100];   // wsum pairs
    __shared__ float2 sbb[100];   // bias pairs
    __shared__ float sd[RPB];
    const int t   = threadIdx.x;
    const int blk = blockIdx.x;

    // fold stage1 partials (L2-hot) + stage wsum/bias into LDS
    if (t < 40) {
        float s = 0.f;
        #pragma unroll
        for (int j = 0; j < PBLK; ++j) s += ws[256 + j * 40 + t];
        sps[t] = s;
    } else if (t == 40) {
        float s = 0.f;
        #pragma unroll
        for (int j = 0; j < PBLK; ++j) s += ws[200 + j];
        spsq = s;
    }
    if (t >= 56 && t < 156) swb[t - 56]  = ((const float2*)ws)[t - 56];
    if (t >= 156)           sbb[t - 156] = ((const float2*)bias)[t - 156];
    __syncthreads();

    // phase 1: threads 0..15 (wave 0) compute d for this block's 16 rows
    if (t < RPB) {
        const int row = blk * RPB + t;
        const float4* xr = (const float4*)(x + row * LAT);
        float ssq = 0.f, dot = 0.f;
        #pragma unroll
        for (int k = 0; k < 10; ++k) {
            float4 v = xr[k];
            ssq += v.x * v.x + v.y * v.y + v.z * v.z + v.w * v.w;
            dot += v.x * sps[4 * k] + v.y * sps[4 * k + 1] +
                   v.z * sps[4 * k + 2] + v.w * sps[4 * k + 3];
        }
        const float d = sqrtf(2048.f * ssq - 2.f * dot + spsq);
        sd[t] = d;
        float mn = d, sm = d;
        #pragma unroll
        for (int off = 8; off > 0; off >>= 1) {   // 16 active lanes, same wave
            mn = fminf(mn, __shfl_down(mn, off, 64));
            sm += __shfl_down(sm, off, 64);
        }
        if (t == 0) {
            ws[1024 + blk] = mn;
            ws[3072 + blk] = sm;
        }
    }
    __syncthreads();

    // phase 2: write this block's 16x200 output slab (1600 float2 pairs)
    float2* o = (float2*)(out + 2);          // 8B-aligned
    const int base = blk * (RPB * 100);
    for (int idx = t; idx < RPB * 100; idx += 256) {
        const int i = idx / 100;             // row within block (magic-mul)
        const int j = idx - i * 100;         // column pair
        const float  dd = sd[i];
        const float2 wv = swb[j];
        const float2 bv = sbb[j];
        float2 r;
        r.x = dd * wv.x + bv.x;
        r.y = dd * wv.y + bv.y;
        o[base + idx] = r;
    }
}

__global__ void pc_finish(const float* __restrict__ ws, float* __restrict__ out) {
    const int t = threadIdx.x;  // 256 threads, 8 partials each
    float mn =  3.4e38f;
    float sm =  0.f;
    #pragma unroll
    for (int j = 0; j < 8; ++j) {
        mn = fminf(mn, ws[1024 + j * 256 + t]);
        sm += ws[3072 + j * 256 + t];
    }
    __shared__ float smn[4], ssm[4];
    #pragma unroll
    for (int off = 32; off > 0; off >>= 1) {
        mn = fminf(mn, __shfl_down(mn, off, 64));
        sm += __shfl_down(sm, off, 64);
    }
    if ((t & 63) == 0) { smn[t >> 6] = mn; ssm[t >> 6] = sm; }
    __syncthreads();
    if (t == 0) {
        out[0] = fminf(fminf(smn[0], smn[1]), fminf(smn[2], smn[3]));
        out[1] = (ssm[0] + ssm[1] + ssm[2] + ssm[3]) * (1.0f / 32768.0f);
    }
}

extern "C" void kernel_launch(void* const* d_in, const int* in_sizes, int n_in,
                              void* d_out, int out_size, void* d_ws, size_t ws_size,
                              hipStream_t stream) {
    const float* x      = (const float*)d_in[0];
    const float* protos = (const float*)d_in[1];
    const float* w      = (const float*)d_in[2];
    const float* bias   = (const float*)d_in[3];
    float* out = (float*)d_out;
    float* ws  = (float*)d_ws;

    pc_stage1<<<NOUT + PBLK, 320, 0, stream>>>(protos, w, ws);
    pc_distout<<<FBLK, 256, 0, stream>>>(x, bias, ws, out);
    pc_finish<<<1, 256, 0, stream>>>(ws, out);
}